// Round 1
// baseline (228.727 us; speedup 1.0000x reference)
//
#include <hip/hip_runtime.h>

#define TPB 256
#define NBLK 2048

__global__ __launch_bounds__(TPB, 8) void CLL_main(
    const float* __restrict__ y_pred,
    const int*   __restrict__ y_true,
    const float* __restrict__ w,
    double*      __restrict__ acc,
    const int B)
{
    const int lane = threadIdx.x & 63;
    const long long wid = (((long long)blockIdx.x * blockDim.x) + threadIdx.x) >> 6;
    const long long nw  = ((long long)gridDim.x * blockDim.x) >> 6;
    const long long chunk_stride = nw * 64;

    float local = 0.0f;

    for (long long base = wid * 64; base < B; base += chunk_stride) {
        // 64 row-indices for this chunk, one per lane (coalesced)
        int myidx = 0;
        if (base + lane < (long long)B) myidx = y_true[base + lane];
        const long long rem = (long long)B - base;
        const int rows = rem >= 64 ? 64 : (int)rem;

        int j = 0;
        for (; j + 4 <= rows; j += 4) {
            const int i0 = __shfl(myidx, j + 0, 64);
            const int i1 = __shfl(myidx, j + 1, 64);
            const int i2 = __shfl(myidx, j + 2, 64);
            const int i3 = __shfl(myidx, j + 3, 64);
            const float* r0 = y_pred + (base + j + 0) * 64;
            const float* r1 = y_pred + (base + j + 1) * 64;
            const float* r2 = y_pred + (base + j + 2) * 64;
            const float* r3 = y_pred + (base + j + 3) * 64;
            float v0 = 0.f, v1 = 0.f, v2 = 0.f, v3 = 0.f;
            // exec-masked loads: untouched 128B lines are not fetched
            if (i0 ? (lane >= i0) : (lane == 0)) v0 = r0[lane];
            if (i1 ? (lane >= i1) : (lane == 0)) v1 = r1[lane];
            if (i2 ? (lane >= i2) : (lane == 0)) v2 = r2[lane];
            if (i3 ? (lane >= i3) : (lane == 0)) v3 = r3[lane];
            // 4 interleaved butterfly reductions (ILP across rows)
            #pragma unroll
            for (int off = 32; off > 0; off >>= 1) {
                v0 += __shfl_xor(v0, off, 64);
                v1 += __shfl_xor(v1, off, 64);
                v2 += __shfl_xor(v2, off, 64);
                v3 += __shfl_xor(v3, off, 64);
            }
            // epilogue spread over lanes 0..3: one log per row, 4 rows at once
            if (lane < 4) {
                const float v = (lane == 0) ? v0 : (lane == 1) ? v1 : (lane == 2) ? v2 : v3;
                const int   i = (lane == 0) ? i0 : (lane == 1) ? i1 : (lane == 2) ? i2 : i3;
                const float lik = fminf(fmaxf(v, 1e-15f), 1.0f);
                local += -__logf(lik) * w[i];
            }
        }
        // generic tail (not taken for B = 2^21, kept for safety)
        for (; j < rows; ++j) {
            const int i0 = __shfl(myidx, j, 64);
            float v0 = 0.f;
            if (i0 ? (lane >= i0) : (lane == 0)) v0 = y_pred[(base + j) * 64 + lane];
            #pragma unroll
            for (int off = 32; off > 0; off >>= 1) v0 += __shfl_xor(v0, off, 64);
            if (lane == 0) {
                const float lik = fminf(fmaxf(v0, 1e-15f), 1.0f);
                local += -__logf(lik) * w[i0];
            }
        }
    }

    // wave-sum of per-lane partials, one double atomic per wave
    #pragma unroll
    for (int off = 32; off > 0; off >>= 1) local += __shfl_xor(local, off, 64);
    if (lane == 0) atomicAdd(acc, (double)local);
}

__global__ void CLL_final(const double* __restrict__ acc,
                          float* __restrict__ out, const int B)
{
    out[0] = (float)(acc[0] / (double)B);
}

extern "C" void kernel_launch(void* const* d_in, const int* in_sizes, int n_in,
                              void* d_out, int out_size, void* d_ws, size_t ws_size,
                              hipStream_t stream) {
    const float* y_pred = (const float*)d_in[0];
    const int*   y_true = (const int*)d_in[1];
    const float* w      = (const float*)d_in[2];
    float* out = (float*)d_out;
    double* acc = (double*)d_ws;

    const int B = in_sizes[1];   // number of rows (y_true has B elements)

    hipMemsetAsync(acc, 0, sizeof(double), stream);
    CLL_main<<<NBLK, TPB, 0, stream>>>(y_pred, y_true, w, acc, B);
    CLL_final<<<1, 1, 0, stream>>>(acc, out, B);
}

// Round 3
// 199.953 us; speedup vs baseline: 1.1439x; 1.1439x over previous
//
#include <hip/hip_runtime.h>

#define TPB 256
#define NBLK 2048

template <int CTRL>
__device__ __forceinline__ float dpp_add(float v) {
    int x = __builtin_amdgcn_update_dpp(0, __float_as_int(v), CTRL, 0xf, 0xf, true);
    return v + __int_as_float(x);
}

__global__ __launch_bounds__(TPB, 8) void CLL_main(
    const float* __restrict__ y_pred,
    const int*   __restrict__ y_true,
    const float* __restrict__ w,
    double*      __restrict__ acc,
    const int B)
{
    const int lane = threadIdx.x & 63;
    const int c    = lane & 15;     // chunk within row (4 floats each)
    const int sub  = lane >> 4;     // row within the quad
    const long long wid = (((long long)blockIdx.x * TPB) + threadIdx.x) >> 6;
    const long long nw  = ((long long)NBLK * TPB) >> 6;
    const long long nquads = ((long long)B + 3) >> 2;

    float local = 0.0f;

    for (long long qi = wid; qi < nquads; qi += nw) {
        const long long r = qi * 4 + sub;
        const bool valid = r < (long long)B;

        int idx = 0;
        if (valid) idx = y_true[r];          // 16 lanes same addr -> cache broadcast

        // masked chunk load: only lines covering the tail [idx..63] are fetched
        float4 v = make_float4(0.f, 0.f, 0.f, 0.f);
        const int b4 = c << 2;
        const bool need = valid && (idx ? (b4 + 3 >= idx) : (c == 0));
        if (need) v = *(const float4*)(y_pred + r * 64 + b4);

        // per-lane masked partial sum of the tail
        const float ms = (b4     >= idx ? v.x : 0.f)
                       + (b4 + 1 >= idx ? v.y : 0.f)
                       + (b4 + 2 >= idx ? v.z : 0.f)
                       + (b4 + 3 >= idx ? v.w : 0.f);
        float s = (idx == 0) ? v.x : ms;     // idx==0: only element 0 (lanes c!=0 hold 0)

        // reduce across the 16-lane group — pure VALU DPP, no LDS pipe
        s = dpp_add<0xB1>(s);    // quad_perm [1,0,3,2]  (xor 1)
        s = dpp_add<0x4E>(s);    // quad_perm [2,3,0,1]  (xor 2)
        s = dpp_add<0x124>(s);   // row_ror:4
        s = dpp_add<0x128>(s);   // row_ror:8

        // epilogue: one log per row; computed wave-wide, accumulated by c==0 lane
        const float lik = fminf(fmaxf(s, 1e-15f), 1.0f);
        const float nll = -__logf(lik) * w[idx];
        local += (c == 0 && valid) ? nll : 0.f;
    }

    // once-per-wave final reduction (6 shuffles total — negligible)
    #pragma unroll
    for (int off = 32; off > 0; off >>= 1) local += __shfl_xor(local, off, 64);
    if (lane == 0) atomicAdd(acc, (double)local);
}

__global__ void CLL_final(const double* __restrict__ acc,
                          float* __restrict__ out, const int B)
{
    out[0] = (float)(acc[0] / (double)B);
}

extern "C" void kernel_launch(void* const* d_in, const int* in_sizes, int n_in,
                              void* d_out, int out_size, void* d_ws, size_t ws_size,
                              hipStream_t stream) {
    const float* y_pred = (const float*)d_in[0];
    const int*   y_true = (const int*)d_in[1];
    const float* w      = (const float*)d_in[2];
    float* out  = (float*)d_out;
    double* acc = (double*)d_ws;

    const int B = in_sizes[1];   // rows (y_true has B elements)

    (void)hipMemsetAsync(acc, 0, sizeof(double), stream);
    CLL_main<<<NBLK, TPB, 0, stream>>>(y_pred, y_true, w, acc, B);
    CLL_final<<<1, 1, 0, stream>>>(acc, out, B);
}

// Round 4
// 78.390 us; speedup vs baseline: 2.9178x; 2.5507x over previous
//
#include <hip/hip_runtime.h>

#define TPB 256
#define NBLK 2048
#define NWAVES (((long long)NBLK * TPB) / 64)   // 8192

template <int CTRL>
__device__ __forceinline__ float dpp_add(float v) {
    int x = __builtin_amdgcn_update_dpp(0, __float_as_int(v), CTRL, 0xf, 0xf, true);
    return v + __int_as_float(x);
}

__device__ __forceinline__ float reduce16(float s) {
    s = dpp_add<0xB1>(s);    // quad_perm xor1
    s = dpp_add<0x4E>(s);    // quad_perm xor2
    s = dpp_add<0x124>(s);   // row_ror:4
    s = dpp_add<0x128>(s);   // row_ror:8
    return s;
}

__device__ __forceinline__ float masked_sum(float4 v, int idx, int b4) {
    float ms = (b4     >= idx ? v.x : 0.f)
             + (b4 + 1 >= idx ? v.y : 0.f)
             + (b4 + 2 >= idx ? v.z : 0.f)
             + (b4 + 3 >= idx ? v.w : 0.f);
    return (idx == 0) ? v.x : ms;   // lanes c!=0 hold v.x==0 when idx==0
}

__global__ __launch_bounds__(TPB, 8) void CLL_main(
    const float* __restrict__ y_pred,
    const int*   __restrict__ y_true,
    const float* __restrict__ w,
    float*       __restrict__ partial,
    const int B)
{
    const int lane = threadIdx.x & 63;
    const int c    = lane & 15;     // chunk within row (4 floats)
    const int sub  = lane >> 4;     // row within quad
    const int b4   = c << 2;
    const long long wid = (((long long)blockIdx.x * TPB) + threadIdx.x) >> 6;
    const long long nw  = NWAVES;
    const long long nquads = ((long long)B + 3) >> 2;

    float local = 0.0f;
    long long qi = wid;

    // main loop: 4 independent quads (16 rows) per iteration
    for (; qi + 3 * nw < nquads; qi += 4 * nw) {
        const long long r0 = (qi         ) * 4 + sub;
        const long long r1 = (qi +     nw) * 4 + sub;
        const long long r2 = (qi + 2 * nw) * 4 + sub;
        const long long r3 = (qi + 3 * nw) * 4 + sub;

        // 4 independent idx loads (one waitcnt covers all)
        const int i0 = y_true[r0];
        const int i1 = y_true[r1];
        const int i2 = y_true[r2];
        const int i3 = y_true[r3];

        // 4 independent exec-masked float4 loads (line elision preserved)
        float4 v0 = {0,0,0,0}, v1 = {0,0,0,0}, v2 = {0,0,0,0}, v3 = {0,0,0,0};
        if (i0 ? (b4 + 3 >= i0) : (c == 0)) v0 = *(const float4*)(y_pred + r0 * 64 + b4);
        if (i1 ? (b4 + 3 >= i1) : (c == 0)) v1 = *(const float4*)(y_pred + r1 * 64 + b4);
        if (i2 ? (b4 + 3 >= i2) : (c == 0)) v2 = *(const float4*)(y_pred + r2 * 64 + b4);
        if (i3 ? (b4 + 3 >= i3) : (c == 0)) v3 = *(const float4*)(y_pred + r3 * 64 + b4);

        // 4 independent pure-VALU reductions
        const float s0 = reduce16(masked_sum(v0, i0, b4));
        const float s1 = reduce16(masked_sum(v1, i1, b4));
        const float s2 = reduce16(masked_sum(v2, i2, b4));
        const float s3 = reduce16(masked_sum(v3, i3, b4));

        if (c == 0) {
            local += -__logf(fminf(fmaxf(s0, 1e-15f), 1.0f)) * w[i0];
            local += -__logf(fminf(fmaxf(s1, 1e-15f), 1.0f)) * w[i1];
            local += -__logf(fminf(fmaxf(s2, 1e-15f), 1.0f)) * w[i2];
            local += -__logf(fminf(fmaxf(s3, 1e-15f), 1.0f)) * w[i3];
        }
    }

    // tail: one quad at a time, with row validity (not taken for B = 2^21)
    for (; qi < nquads; qi += nw) {
        const long long r = qi * 4 + sub;
        const bool valid = r < (long long)B;
        int idx = 0;
        if (valid) idx = y_true[r];
        float4 v = {0,0,0,0};
        if (valid && (idx ? (b4 + 3 >= idx) : (c == 0)))
            v = *(const float4*)(y_pred + r * 64 + b4);
        const float s = reduce16(masked_sum(v, idx, b4));
        if (c == 0 && valid)
            local += -__logf(fminf(fmaxf(s, 1e-15f), 1.0f)) * w[idx];
    }

    // wave sum -> one partial per wave (no atomics, no memset needed)
    #pragma unroll
    for (int off = 32; off; off >>= 1) local += __shfl_xor(local, off, 64);
    if (lane == 0) partial[wid] = local;
}

__global__ __launch_bounds__(1024) void CLL_final(
    const float* __restrict__ partial, float* __restrict__ out, const int B)
{
    __shared__ double red[16];
    double s = 0.0;
    for (int i = threadIdx.x; i < (int)NWAVES; i += 1024) s += (double)partial[i];
    #pragma unroll
    for (int off = 32; off; off >>= 1) s += __shfl_xor(s, off, 64);
    if ((threadIdx.x & 63) == 0) red[threadIdx.x >> 6] = s;
    __syncthreads();
    if (threadIdx.x == 0) {
        double t = 0.0;
        #pragma unroll
        for (int i = 0; i < 16; ++i) t += red[i];
        out[0] = (float)(t / (double)B);
    }
}

extern "C" void kernel_launch(void* const* d_in, const int* in_sizes, int n_in,
                              void* d_out, int out_size, void* d_ws, size_t ws_size,
                              hipStream_t stream) {
    const float* y_pred = (const float*)d_in[0];
    const int*   y_true = (const int*)d_in[1];
    const float* w      = (const float*)d_in[2];
    float* out  = (float*)d_out;
    float* part = (float*)d_ws;

    const int B = in_sizes[1];   // rows (y_true has B elements)

    CLL_main<<<NBLK, TPB, 0, stream>>>(y_pred, y_true, w, part, B);
    CLL_final<<<1, 1024, 0, stream>>>(part, out, B);
}

// Round 5
// 74.485 us; speedup vs baseline: 3.0708x; 1.0524x over previous
//
#include <hip/hip_runtime.h>

#define TPB 256
#define NBLK 2048
#define NW (NBLK * TPB / 64)   // 8192 waves

template <int CTRL>
__device__ __forceinline__ float dpp_add(float v) {
    int x = __builtin_amdgcn_update_dpp(0, __float_as_int(v), CTRL, 0xf, 0xf, true);
    return v + __int_as_float(x);
}

__device__ __forceinline__ float reduce16(float s) {
    s = dpp_add<0xB1>(s);    // quad_perm xor1
    s = dpp_add<0x4E>(s);    // quad_perm xor2
    s = dpp_add<0x124>(s);   // row_ror:4
    s = dpp_add<0x128>(s);   // row_ror:8
    return s;
}

__device__ __forceinline__ float masked_sum(float4 v, int idx, int b4) {
    float ms = (b4     >= idx ? v.x : 0.f)
             + (b4 + 1 >= idx ? v.y : 0.f)
             + (b4 + 2 >= idx ? v.z : 0.f)
             + (b4 + 3 >= idx ? v.w : 0.f);
    return (idx == 0) ? v.x : ms;   // lanes c!=0 hold v.x==0 when idx==0
}

__device__ __forceinline__ float nll_term(float s, int i, const float* __restrict__ w) {
    return -__logf(fminf(fmaxf(s, 1e-15f), 1.0f)) * w[i];
}

__global__ __launch_bounds__(TPB, 8) void CLL_main(
    const float* __restrict__ y_pred,
    const int*   __restrict__ y_true,
    const float* __restrict__ w,
    float*       __restrict__ partial,
    const int B)
{
    const int lane = threadIdx.x & 63;
    const int wv   = threadIdx.x >> 6;   // wave within block (0..3)
    const int c    = lane & 15;          // chunk within row (4 floats)
    const int sub  = lane >> 4;          // row within quad
    const int b4   = c << 2;
    const int wid  = (blockIdx.x * TPB + threadIdx.x) >> 6;   // fits int32
    const int nw   = NW;
    const int nquads = (B + 3) >> 2;     // B = 2^21 -> 2^19, int32-safe

    float local = 0.0f;
    int qi = wid;

    if (qi + 3 * nw < nquads) {
        // prologue: idx for first iteration
        int i0 = y_true[(qi         ) * 4 + sub];
        int i1 = y_true[(qi +     nw) * 4 + sub];
        int i2 = y_true[(qi + 2 * nw) * 4 + sub];
        int i3 = y_true[(qi + 3 * nw) * 4 + sub];
        for (;;) {
            const int r0 = (qi         ) * 4 + sub;
            const int r1 = (qi +     nw) * 4 + sub;
            const int r2 = (qi + 2 * nw) * 4 + sub;
            const int r3 = (qi + 3 * nw) * 4 + sub;

            // issue the 4 masked y_pred loads first (critical path)
            float4 v0 = {0,0,0,0}, v1 = {0,0,0,0}, v2 = {0,0,0,0}, v3 = {0,0,0,0};
            if (i0 ? (b4 + 3 >= i0) : (c == 0)) v0 = *(const float4*)(y_pred + r0 * 64 + b4);
            if (i1 ? (b4 + 3 >= i1) : (c == 0)) v1 = *(const float4*)(y_pred + r1 * 64 + b4);
            if (i2 ? (b4 + 3 >= i2) : (c == 0)) v2 = *(const float4*)(y_pred + r2 * 64 + b4);
            if (i3 ? (b4 + 3 >= i3) : (c == 0)) v3 = *(const float4*)(y_pred + r3 * 64 + b4);

            // prefetch next iteration's idx — latency hides under the loads above
            const int qn = qi + 4 * nw;
            const bool more = (qn + 3 * nw < nquads);   // wave-uniform
            int n0 = 0, n1 = 0, n2 = 0, n3 = 0;
            if (more) {
                n0 = y_true[(qn         ) * 4 + sub];
                n1 = y_true[(qn +     nw) * 4 + sub];
                n2 = y_true[(qn + 2 * nw) * 4 + sub];
                n3 = y_true[(qn + 3 * nw) * 4 + sub];
            }

            const float s0 = reduce16(masked_sum(v0, i0, b4));
            const float s1 = reduce16(masked_sum(v1, i1, b4));
            const float s2 = reduce16(masked_sum(v2, i2, b4));
            const float s3 = reduce16(masked_sum(v3, i3, b4));

            if (c == 0) {
                local += nll_term(s0, i0, w);
                local += nll_term(s1, i1, w);
                local += nll_term(s2, i2, w);
                local += nll_term(s3, i3, w);
            }

            qi = qn;
            if (!more) break;
            i0 = n0; i1 = n1; i2 = n2; i3 = n3;
        }
    }

    // tail: one quad at a time with validity (not taken for B = 2^21)
    for (; qi < nquads; qi += nw) {
        const int r = qi * 4 + sub;
        const bool valid = r < B;
        int idx = 0;
        if (valid) idx = y_true[r];
        float4 v = {0,0,0,0};
        if (valid && (idx ? (b4 + 3 >= idx) : (c == 0)))
            v = *(const float4*)(y_pred + r * 64 + b4);
        const float s = reduce16(masked_sum(v, idx, b4));
        if (c == 0 && valid) local += nll_term(s, idx, w);
    }

    // wave sum, then block sum via LDS -> one partial per block
    #pragma unroll
    for (int off = 32; off; off >>= 1) local += __shfl_xor(local, off, 64);
    __shared__ float bred[TPB / 64];
    if (lane == 0) bred[wv] = local;
    __syncthreads();
    if (threadIdx.x == 0)
        partial[blockIdx.x] = bred[0] + bred[1] + bred[2] + bred[3];
}

__global__ __launch_bounds__(1024) void CLL_final(
    const float* __restrict__ partial, float* __restrict__ out, const int B)
{
    __shared__ double red[16];
    double s = 0.0;
    for (int i = threadIdx.x; i < NBLK; i += 1024) s += (double)partial[i];
    #pragma unroll
    for (int off = 32; off; off >>= 1) s += __shfl_xor(s, off, 64);
    if ((threadIdx.x & 63) == 0) red[threadIdx.x >> 6] = s;
    __syncthreads();
    if (threadIdx.x == 0) {
        double t = 0.0;
        #pragma unroll
        for (int i = 0; i < 16; ++i) t += red[i];
        out[0] = (float)(t / (double)B);
    }
}

extern "C" void kernel_launch(void* const* d_in, const int* in_sizes, int n_in,
                              void* d_out, int out_size, void* d_ws, size_t ws_size,
                              hipStream_t stream) {
    const float* y_pred = (const float*)d_in[0];
    const int*   y_true = (const int*)d_in[1];
    const float* w      = (const float*)d_in[2];
    float* out  = (float*)d_out;
    float* part = (float*)d_ws;

    const int B = in_sizes[1];   // rows (y_true has B elements)

    CLL_main<<<NBLK, TPB, 0, stream>>>(y_pred, y_true, w, part, B);
    CLL_final<<<1, 1024, 0, stream>>>(part, out, B);
}